// Round 25
// baseline (306.484 us; speedup 1.0000x reference)
//
#include <hip/hip_runtime.h>

#define N_NODES 100000
#define N_EDGES 1600000
#define N_GRAPHS 256
#define NBKT 196                          // ceil(100000/512) buckets of 512 nodes
#define BKT_CAP 16384                     // slots per bucket region (expected fill ~8192)
#define B_BLOCKS 782                      // ceil(1600000/2048) bucket blocks
#define MM1_BLOCKS 3125                   // 100000 / 32 exactly
#define BM_BLOCKS (NBKT + MM1_BLOCKS)     // 3321: bid%17==0 -> build, else mm1

__device__ __forceinline__ float lrelu(float v) { return v > 0.f ? v : 0.01f * v; }

// bf16 storage helpers (RNE)
__device__ __forceinline__ unsigned short f2bf(float f) {
    unsigned int u = __float_as_uint(f);
    return (unsigned short)((u + 0x7FFFu + ((u >> 16) & 1u)) >> 16);
}
__device__ __forceinline__ float bf2f(unsigned short h) {
    return __uint_as_float(((unsigned int)h) << 16);
}
__device__ __forceinline__ float blo(unsigned int v) { return __uint_as_float(v << 16); }
__device__ __forceinline__ float bhi(unsigned int v) { return __uint_as_float(v & 0xFFFF0000u); }

// ============ phase A1: bucket edges by dst/512 (2048 edges/block, reg-cached) ============
__global__ void bucket_only(const int* __restrict__ src, const int* __restrict__ dst,
                            int* __restrict__ bucketCnt, unsigned int* __restrict__ bkt) {
    __shared__ int lcnt[784], loff[784], lcnt2[784];
    int fi = blockIdx.x;                  // 0..781
    int tid = threadIdx.x;
    for (int i = tid; i < 784; i += 256) { lcnt[i] = 0; lcnt2[i] = 0; }
    __syncthreads();
    int sub = tid & 3;
    int e0 = fi * 2048 + tid;
    int dcache[8], scache[8];
#pragma unroll
    for (int i = 0; i < 8; ++i) {
        int e = e0 + i * 256;
        if (e < N_EDGES) {
            dcache[i] = dst[e];
            scache[i] = src[e];
            atomicAdd(&lcnt[sub * 196 + (dcache[i] >> 9)], 1);
        }
    }
    __syncthreads();
    if (tid < NBKT) {
        int c0 = lcnt[tid], c1 = lcnt[196 + tid], c2 = lcnt[392 + tid], c3 = lcnt[588 + tid];
        int tot = c0 + c1 + c2 + c3;
        int goff = (tot > 0) ? atomicAdd(&bucketCnt[tid], tot) : 0;
        loff[tid] = goff;
        loff[196 + tid] = goff + c0;
        loff[392 + tid] = goff + c0 + c1;
        loff[588 + tid] = goff + c0 + c1 + c2;
    }
    __syncthreads();
#pragma unroll
    for (int i = 0; i < 8; ++i) {
        int e = e0 + i * 256;
        if (e < N_EDGES) {
            int d = dcache[i];
            int b = d >> 9;
            int pos = loff[sub * 196 + b] + atomicAdd(&lcnt2[sub * 196 + b], 1);
            if (pos < BKT_CAP)   // capacity guard (uniform dst: never hit)
                bkt[(size_t)b * BKT_CAP + pos] =
                    ((unsigned int)(d & 511) << 17) | (unsigned int)scache[i];
        }
    }
}

// ============ phase A2 FUSED: build_bucket (196 blocks)  ∥  matmul L1 (3125 blocks) ============
// bid%17==0 -> build role (LDS-heavy, small grid hides under mm1's x-stream).
__global__ void build_and_mm1(const unsigned int* __restrict__ bkt, const int* __restrict__ bucketCnt,
                              int* __restrict__ base, int* __restrict__ adj,
                              const float* __restrict__ x, const float* __restrict__ W1,
                              unsigned short* __restrict__ T1) {
    __shared__ float lds[32 * 132 + 128 * 16];   // 25088 B, unioned across roles
    int bid = blockIdx.x;
    int tid = threadIdx.x;
    if (bid % 17 == 0) {
        // ---- build role: b = bid/17 in 0..195 ----
        int* ldeg = (int*)lds;
        int* lofs = ldeg + 512;
        int* ssum = lofs + 512;
        int b = bid / 17;
        // exclusive prefix of bucketCnt over buckets < b (196 values, scan in LDS)
        ssum[tid] = (tid < NBKT) ? bucketCnt[tid] : 0;
        __syncthreads();
        for (int off = 1; off < 256; off <<= 1) {
            int add = (tid >= off) ? ssum[tid - off] : 0;
            __syncthreads();
            ssum[tid] += add;
            __syncthreads();
        }
        int gbase = (b > 0) ? ssum[b - 1] : 0;
        int cnt = min(bucketCnt[b], BKT_CAP);
        int nstart = b * 512;
        int nn = min(512, N_NODES - nstart);
        const unsigned int* seg = bkt + (size_t)b * BKT_CAP;
        for (int i = tid; i < 512; i += 256) ldeg[i] = 0;
        __syncthreads();
        for (int e = tid; e < cnt; e += 256) atomicAdd(&ldeg[seg[e] >> 17], 1);
        __syncthreads();
        // exclusive scan of ldeg[0..511] with 256 threads (2 elems/thread)
        int a0 = ldeg[2 * tid], a1 = ldeg[2 * tid + 1];
        __syncthreads();
        ssum[tid] = a0 + a1;
        __syncthreads();
        for (int off = 1; off < 256; off <<= 1) {
            int add = (tid >= off) ? ssum[tid - off] : 0;
            __syncthreads();
            ssum[tid] += add;
            __syncthreads();
        }
        int prev = (tid > 0) ? ssum[tid - 1] : 0;
        lofs[2 * tid] = prev;
        lofs[2 * tid + 1] = prev + a0;
        __syncthreads();
        for (int i = tid; i < nn; i += 256) base[nstart + i] = gbase + lofs[i];
        if (b == 0 && tid == 0) base[N_NODES] = N_EDGES;
        for (int i = tid; i < 512; i += 256) ldeg[i] = 0;
        __syncthreads();
        for (int e = tid; e < cnt; e += 256) {
            unsigned int v = seg[e];
            int dl = (int)(v >> 17);
            int pos = atomicAdd(&ldeg[dl], 1);
            adj[gbase + lofs[dl] + pos] = (int)(v & 0x1FFFFu);
        }
    } else {
        // ---- mm1 role: T1 = x @ W1 [128->16], 32-node tile, float4 xs reads ----
        int mb = bid - bid / 17 - 1;      // 0..3124
        float* xs = lds;                  // 32 rows x 132 (padded, 16B-aligned rows)
        float* wsm = lds + 32 * 132;      // 128 x 16 (original layout)
        const int n0 = mb * 32;           // 32*3125 = 100000 exactly
        for (int i = tid; i < 128 * 16; i += 256) wsm[i] = W1[i];
        const float4* X4 = (const float4*)x;     // 32 float4 per row
        for (int i = tid; i < 32 * 32; i += 256) {
            int r2 = i >> 5, c = i & 31;
            ((float4*)(xs + r2 * 132))[c] = X4[(size_t)(n0 + r2) * 32 + c];
        }
        __syncthreads();
        int r2 = tid >> 3, jp = tid & 7;  // 32 rows x 8 pairs = 256 outputs
        float a0 = 0.f, a1 = 0.f;
        const float4* xr4 = (const float4*)(xs + r2 * 132);
#pragma unroll
        for (int k4 = 0; k4 < 32; ++k4) {
            float4 xv = xr4[k4];
            float2 w0 = *(const float2*)(wsm + (4 * k4 + 0) * 16 + 2 * jp);
            float2 w1 = *(const float2*)(wsm + (4 * k4 + 1) * 16 + 2 * jp);
            float2 w2 = *(const float2*)(wsm + (4 * k4 + 2) * 16 + 2 * jp);
            float2 w3 = *(const float2*)(wsm + (4 * k4 + 3) * 16 + 2 * jp);
            a0 = fmaf(xv.x, w0.x, a0); a1 = fmaf(xv.x, w0.y, a1);
            a0 = fmaf(xv.y, w1.x, a0); a1 = fmaf(xv.y, w1.y, a1);
            a0 = fmaf(xv.z, w2.x, a0); a1 = fmaf(xv.z, w2.y, a1);
            a0 = fmaf(xv.w, w3.x, a0); a1 = fmaf(xv.w, w3.y, a1);
        }
        ((unsigned int*)T1)[(size_t)(n0 + r2) * 8 + jp] = ((unsigned int)f2bf(a1) << 16) | f2bf(a0);
    }
}

// ============ register-tiled matmul: X[N,DIN]@W[DIN,DOUT] -> bf16 rows ============
template <int DIN, int DOUT, int ROWS, bool BIAS, bool RELU>
__global__ void matmul_rt(const unsigned int* __restrict__ X2, const float* __restrict__ W,
                          unsigned short* __restrict__ T, const float* __restrict__ bias) {
    constexpr int PAIRS = DOUT / 2;              // 16, 32, 25
    constexpr int PT = (PAIRS + 3) / 4;          // pair-tiles: 4, 8, 7
    constexpr int RT = ROWS / 4;                 // row-tiles
    constexpr int XST = DIN + 1;                 // odd stride -> conflict-light
    __shared__ float xs[ROWS * XST];
    __shared__ float wsm[DIN * DOUT + 8];        // +8: pad-jp reads stay in-bounds
    const int n0 = blockIdx.x * ROWS;
    const bool full = (n0 + ROWS <= N_NODES);
    int tid = threadIdx.x;
    for (int i = tid; i < DIN * DOUT; i += 256) wsm[i] = W[i];
    constexpr int V = DIN / 2;                   // uints per row
    for (int i = tid; i < ROWS * V; i += 256) {
        int r = i / V, c = i - r * V;
        int node = n0 + r;
        unsigned int v = (full || node < N_NODES) ? X2[(size_t)node * V + c] : 0u;
        xs[r * XST + 2 * c]     = blo(v);
        xs[r * XST + 2 * c + 1] = bhi(v);
    }
    __syncthreads();
    if (tid >= RT * PT) return;
    int rt = tid / PT, pt = tid - rt * PT;
    const float* xr0 = xs + (rt * 4) * XST;
    const float* wp = wsm + 2 * (pt * 4);
    float2 acc[4][4];
#pragma unroll
    for (int i = 0; i < 4; ++i)
#pragma unroll
        for (int j = 0; j < 4; ++j) acc[i][j] = make_float2(0.f, 0.f);
#pragma unroll 4
    for (int k = 0; k < DIN; ++k) {
        float xv0 = xr0[k];
        float xv1 = xr0[XST + k];
        float xv2 = xr0[2 * XST + k];
        float xv3 = xr0[3 * XST + k];
        const float* wr = wp + k * DOUT;
        float2 w0 = *(const float2*)(wr);
        float2 w1 = *(const float2*)(wr + 2);
        float2 w2 = *(const float2*)(wr + 4);
        float2 w3 = *(const float2*)(wr + 6);
        acc[0][0].x = fmaf(xv0, w0.x, acc[0][0].x); acc[0][0].y = fmaf(xv0, w0.y, acc[0][0].y);
        acc[0][1].x = fmaf(xv0, w1.x, acc[0][1].x); acc[0][1].y = fmaf(xv0, w1.y, acc[0][1].y);
        acc[0][2].x = fmaf(xv0, w2.x, acc[0][2].x); acc[0][2].y = fmaf(xv0, w2.y, acc[0][2].y);
        acc[0][3].x = fmaf(xv0, w3.x, acc[0][3].x); acc[0][3].y = fmaf(xv0, w3.y, acc[0][3].y);
        acc[1][0].x = fmaf(xv1, w0.x, acc[1][0].x); acc[1][0].y = fmaf(xv1, w0.y, acc[1][0].y);
        acc[1][1].x = fmaf(xv1, w1.x, acc[1][1].x); acc[1][1].y = fmaf(xv1, w1.y, acc[1][1].y);
        acc[1][2].x = fmaf(xv1, w2.x, acc[1][2].x); acc[1][2].y = fmaf(xv1, w2.y, acc[1][2].y);
        acc[1][3].x = fmaf(xv1, w3.x, acc[1][3].x); acc[1][3].y = fmaf(xv1, w3.y, acc[1][3].y);
        acc[2][0].x = fmaf(xv2, w0.x, acc[2][0].x); acc[2][0].y = fmaf(xv2, w0.y, acc[2][0].y);
        acc[2][1].x = fmaf(xv2, w1.x, acc[2][1].x); acc[2][1].y = fmaf(xv2, w1.y, acc[2][1].y);
        acc[2][2].x = fmaf(xv2, w2.x, acc[2][2].x); acc[2][2].y = fmaf(xv2, w2.y, acc[2][2].y);
        acc[2][3].x = fmaf(xv2, w3.x, acc[2][3].x); acc[2][3].y = fmaf(xv2, w3.y, acc[2][3].y);
        acc[3][0].x = fmaf(xv3, w0.x, acc[3][0].x); acc[3][0].y = fmaf(xv3, w0.y, acc[3][0].y);
        acc[3][1].x = fmaf(xv3, w1.x, acc[3][1].x); acc[3][1].y = fmaf(xv3, w1.y, acc[3][1].y);
        acc[3][2].x = fmaf(xv3, w2.x, acc[3][2].x); acc[3][2].y = fmaf(xv3, w2.y, acc[3][2].y);
        acc[3][3].x = fmaf(xv3, w3.x, acc[3][3].x); acc[3][3].y = fmaf(xv3, w3.y, acc[3][3].y);
    }
    unsigned int* Tu = (unsigned int*)T;
#pragma unroll
    for (int i = 0; i < 4; ++i) {
        int node = n0 + rt * 4 + i;
        if (full || node < N_NODES) {
#pragma unroll
            for (int j = 0; j < 4; ++j) {
                int jp = pt * 4 + j;
                if (PAIRS % 4 == 0 || jp < PAIRS) {
                    float a0 = acc[i][j].x, a1 = acc[i][j].y;
                    if (BIAS) { a0 += bias[2 * jp]; a1 += bias[2 * jp + 1]; }
                    if (RELU) { a0 = lrelu(a0); a1 = lrelu(a1); }
                    Tu[(size_t)node * PAIRS + jp] = ((unsigned int)f2bf(a1) << 16) | f2bf(a0);
                }
            }
        }
    }
}

// ============ CSR gather-aggregate (bf16 pairs), 16-deep ILP ============
template <int DOUT, bool BIAS, bool RELU>
__global__ void gather_agg_bf16(const unsigned short* __restrict__ T, const int* __restrict__ base,
                                const int* __restrict__ adj, const float* __restrict__ b,
                                unsigned short* __restrict__ out) {
    constexpr int PAIRS = DOUT / 2;                       // 8, 16, 25
    int gi = blockIdx.x * 256 + threadIdx.x;
    int node = gi / PAIRS;                                // const div -> magic mul
    int j = gi - node * PAIRS;
    if (node >= N_NODES) return;
    const unsigned int* Tu = (const unsigned int*)T;
    int e0 = base[node], e1 = base[node + 1];
    float a0 = 0.f, a1 = 0.f, c0 = 0.f, c1 = 0.f;
    int k = e0;
    for (; k + 15 < e1; k += 16) {
        int s[16];
#pragma unroll
        for (int t = 0; t < 16; ++t) s[t] = adj[k + t];
        unsigned int v[16];
#pragma unroll
        for (int t = 0; t < 16; ++t) v[t] = Tu[(size_t)s[t] * PAIRS + j];
#pragma unroll
        for (int t = 0; t < 16; ++t) {
            if (t & 1) { c0 += blo(v[t]); c1 += bhi(v[t]); }
            else       { a0 += blo(v[t]); a1 += bhi(v[t]); }
        }
    }
    for (; k + 3 < e1; k += 4) {
        int s0 = adj[k], s1 = adj[k + 1], s2 = adj[k + 2], s3 = adj[k + 3];
        unsigned int v0 = Tu[(size_t)s0 * PAIRS + j];
        unsigned int v1 = Tu[(size_t)s1 * PAIRS + j];
        unsigned int v2 = Tu[(size_t)s2 * PAIRS + j];
        unsigned int v3 = Tu[(size_t)s3 * PAIRS + j];
        a0 += blo(v0); a1 += bhi(v0);
        c0 += blo(v1); c1 += bhi(v1);
        a0 += blo(v2); a1 += bhi(v2);
        c0 += blo(v3); c1 += bhi(v3);
    }
    for (; k < e1; ++k) {
        int s = adj[k];
        unsigned int v = Tu[(size_t)s * PAIRS + j];
        a0 += blo(v); a1 += bhi(v);
    }
    a0 += c0; a1 += c1;
    if (BIAS) { a0 += b[2 * j]; a1 += b[2 * j + 1]; }
    if (RELU) { a0 = lrelu(a0); a1 = lrelu(a1); }
    ((unsigned int*)out)[(size_t)node * PAIRS + j] = ((unsigned int)f2bf(a1) << 16) | f2bf(a0);
}

// ============ BatchNorm stats (bf16 row input) ============
__global__ void bn_partial_kernel(const unsigned short* __restrict__ H, float* __restrict__ sum,
                                  float* __restrict__ ssum) {
    int tid = threadIdx.x;
    int j = tid % 50;
    int sub = tid / 50;
    float s = 0.f, ss = 0.f;
    if (tid < 250) {
        for (int node = blockIdx.x * 5 + sub; node < N_NODES; node += gridDim.x * 5) {
            float v = bf2f(H[(size_t)node * 50 + j]);
            s += v;
            ss += v * v;
        }
    }
    __shared__ float ls[256], lss[256];
    ls[tid] = s;
    lss[tid] = ss;
    __syncthreads();
    if (tid < 50) {
        float a = ls[tid] + ls[tid + 50] + ls[tid + 100] + ls[tid + 150] + ls[tid + 200];
        float c = lss[tid] + lss[tid + 50] + lss[tid + 100] + lss[tid + 150] + lss[tid + 200];
        atomicAdd(&sum[tid], a);
        atomicAdd(&ssum[tid], c);
    }
}

// ============ setup: graph bounds (batch sorted) + zero bucketCnt/bnsum/bnssum ============
__global__ void setup_kernel(const int* __restrict__ batch, int* __restrict__ bounds,
                             int* __restrict__ bucketCnt, float* __restrict__ bnsum,
                             float* __restrict__ bnssum) {
    int tid = threadIdx.x;
    if (blockIdx.x == 0) {
        bucketCnt[tid] = 0;
    } else if (tid < 64) {
        bnsum[tid] = 0.f;
        bnssum[tid] = 0.f;
    }
    int g = blockIdx.x * 256 + tid;
    if (g > N_GRAPHS) return;
    int lo = 0, hi = N_NODES;
    while (lo < hi) {
        int mid = (lo + hi) >> 1;
        if (batch[mid] < g) lo = mid + 1; else hi = mid;
    }
    bounds[g] = lo;
}

// ============ BN finalize (inline) + lrelu + segmented pool: one block per graph ============
__global__ void pool_seg_kernel(const unsigned short* __restrict__ H, const int* __restrict__ bounds,
                                const float* __restrict__ bnsum, const float* __restrict__ bnssum,
                                const float* __restrict__ gamma, const float* __restrict__ beta,
                                float* __restrict__ G) {
    int g = blockIdx.x;
    int s = bounds[g], e = bounds[g + 1];
    int tid = threadIdx.x;
    int j = tid % 50;
    int sub = tid / 50;     // 0..4 for tid<250
    float acc = 0.f;
    if (tid < 250) {
        float m = bnsum[j] / (float)N_NODES;
        float var = bnssum[j] / (float)N_NODES - m * m;
        float rs = rsqrtf(fmaxf(var, 0.f) + 1e-5f);
        float scale = rs * gamma[j];
        float shift = beta[j] - m * scale;
        for (int n = s + sub; n < e; n += 5) {
            float v = fmaf(bf2f(H[(size_t)n * 50 + j]), scale, shift);
            acc += lrelu(v);
        }
    }
    __shared__ float ls[256];
    ls[tid] = acc;
    __syncthreads();
    if (tid < 50) {
        G[g * 50 + tid] = ls[tid] + ls[tid + 50] + ls[tid + 100] + ls[tid + 150] + ls[tid + 200];
    }
}

// ============ MLP head: 8 blocks x 32 graphs, weights staged in LDS ============
__global__ void mlp_kernel(const float* __restrict__ G,
                           const float* __restrict__ fc1W, const float* __restrict__ fc1b,
                           const float* __restrict__ fc2W, const float* __restrict__ fc2b,
                           const float* __restrict__ fc3W, const float* __restrict__ fc3b,
                           float* __restrict__ out) {
    __shared__ float lw[2192];   // fc1W 1500 | fc1b 30 | fc2W 600 | fc2b 20 | fc3W 40 | fc3b 2
    int tid = threadIdx.x;
    for (int i = tid; i < 1500; i += 256) lw[i] = fc1W[i];
    for (int i = tid; i < 30; i += 256) lw[1500 + i] = fc1b[i];
    for (int i = tid; i < 600; i += 256) lw[1530 + i] = fc2W[i];
    for (int i = tid; i < 20; i += 256) lw[2130 + i] = fc2b[i];
    for (int i = tid; i < 40; i += 256) lw[2150 + i] = fc3W[i];
    for (int i = tid; i < 2; i += 256) lw[2190 + i] = fc3b[i];
    __syncthreads();
    int g = blockIdx.x * 32 + tid;
    if (tid >= 32 || g >= N_GRAPHS) return;
    float a[50];
#pragma unroll
    for (int k = 0; k < 50; ++k) a[k] = G[g * 50 + k];
    float h1[30];
#pragma unroll
    for (int j = 0; j < 30; ++j) {
        float acc = lw[1500 + j];
#pragma unroll
        for (int k = 0; k < 50; ++k) acc = fmaf(a[k], lw[k * 30 + j], acc);
        h1[j] = lrelu(acc);
    }
    float h2[20];
#pragma unroll
    for (int j = 0; j < 20; ++j) {
        float acc = lw[2130 + j];
#pragma unroll
        for (int k = 0; k < 30; ++k) acc = fmaf(h1[k], lw[1530 + k * 20 + j], acc);
        h2[j] = lrelu(acc);
    }
    float z0 = lw[2190], z1 = lw[2191];
#pragma unroll
    for (int k = 0; k < 20; ++k) {
        z0 = fmaf(h2[k], lw[2150 + k * 2 + 0], z0);
        z1 = fmaf(h2[k], lw[2150 + k * 2 + 1], z1);
    }
    float m = fmaxf(z0, z1);
    float lse = m + logf(expf(z0 - m) + expf(z1 - m));
    out[g * 2 + 0] = z0 - lse;
    out[g * 2 + 1] = z1 - lse;
}

extern "C" void kernel_launch(void* const* d_in, const int* in_sizes, int n_in,
                              void* d_out, int out_size, void* d_ws, size_t ws_size,
                              hipStream_t stream) {
    const float* x     = (const float*)d_in[0];
    const int*   ei    = (const int*)d_in[1];
    const int*   batch = (const int*)d_in[2];
    const float* W1 = (const float*)d_in[3];  const float* b1 = (const float*)d_in[4];
    const float* W2 = (const float*)d_in[5];  const float* b2 = (const float*)d_in[6];
    const float* W3 = (const float*)d_in[7];  const float* b3 = (const float*)d_in[8];
    const float* W4 = (const float*)d_in[9];  const float* b4 = (const float*)d_in[10];
    const float* bng = (const float*)d_in[11]; const float* bnb = (const float*)d_in[12];
    const float* fc1W = (const float*)d_in[13]; const float* fc1b = (const float*)d_in[14];
    const float* fc2W = (const float*)d_in[15]; const float* fc2b = (const float*)d_in[16];
    const float* fc3W = (const float*)d_in[17]; const float* fc3b = (const float*)d_in[18];

    const int* src = ei;
    const int* dst = ei + N_EDGES;

    // ---- workspace layout ----
    char* w = (char*)d_ws;
    unsigned short* bufA = (unsigned short*)w;      w += (size_t)6400000 * 2;  // 12.8 MB
    unsigned short* bufB = (unsigned short*)w;      w += (size_t)6400000 * 2;  // 12.8 MB
    int*   adj  = (int*)w;                          w += (size_t)N_EDGES * 4;  // 6.4 MB
    unsigned int* bkt = (unsigned int*)w;           w += (size_t)NBKT * BKT_CAP * 4;  // 12.8 MB
    int*   base = (int*)w;                          w += (size_t)(N_NODES + 1) * 4;
    int*   bucketCnt = (int*)w;                     w += 256 * 4;
    float* bnsum = (float*)w;                       w += 64 * 4;
    float* bnssum = (float*)w;                      w += 64 * 4;
    int*   bounds = (int*)w;                        w += (N_GRAPHS + 1) * 4;
    float* G    = (float*)w;                        w += (size_t)N_GRAPHS * 50 * 4;

    dim3 blk(256);

    // ---- setup: bounds + zero bucketCnt/bn accumulators (one kernel) ----
    setup_kernel<<<2, 256, 0, stream>>>(batch, bounds, bucketCnt, bnsum, bnssum);

    // ---- phase A1: bucket edges (782 blocks x 2048 edges) ----
    bucket_only<<<B_BLOCKS, blk, 0, stream>>>(src, dst, bucketCnt, bkt);

    // ---- phase A2 FUSED: build_bucket (196) ∥ matmul L1 (3125) ----
    build_and_mm1<<<BM_BLOCKS, blk, 0, stream>>>(bkt, bucketCnt, base, adj, x, W1, bufA);

    // ---- L1 agg: h1 = lrelu(agg(T1) + b1) ----
    gather_agg_bf16<16, true, true><<<(N_NODES * 8 + 255) / 256, blk, 0, stream>>>(bufA, base, adj, b1, bufB);

    // ---- L2: s2 = agg(h1); h2 = lrelu(s2 @ W2 + b2) [16->32] ----
    gather_agg_bf16<16, false, false><<<(N_NODES * 8 + 255) / 256, blk, 0, stream>>>(bufB, base, adj, nullptr, bufA);
    matmul_rt<16, 32, 256, true, true><<<(N_NODES + 255) / 256, blk, 0, stream>>>((const unsigned int*)bufA, W2, bufB, b2);

    // ---- L3: s3 = agg(h2); h3 = lrelu(s3 @ W3 + b3) [32->64] ----
    gather_agg_bf16<32, false, false><<<(N_NODES * 16 + 255) / 256, blk, 0, stream>>>(bufB, base, adj, nullptr, bufA);
    matmul_rt<32, 64, 128, true, true><<<(N_NODES + 127) / 128, blk, 0, stream>>>((const unsigned int*)bufA, W3, bufB, b3);

    // ---- L4: T4 = h3 @ W4 [64->50]; h4 = agg(T4) + b4 ----
    matmul_rt<64, 50, 128, false, false><<<(N_NODES + 127) / 128, blk, 0, stream>>>((const unsigned int*)bufB, W4, bufA, nullptr);
    gather_agg_bf16<50, true, false><<<(N_NODES * 25 + 255) / 256, blk, 0, stream>>>(bufA, base, adj, b4, bufB);

    // ---- BatchNorm stats ----
    bn_partial_kernel<<<256, blk, 0, stream>>>(bufB, bnsum, bnssum);

    // ---- BN finalize (inline) + lrelu + segmented pool (no atomics) ----
    pool_seg_kernel<<<N_GRAPHS, blk, 0, stream>>>(bufB, bounds, bnsum, bnssum, bng, bnb, G);

    // ---- MLP head ----
    mlp_kernel<<<8, 256, 0, stream>>>(G, fc1W, fc1b, fc2W, fc2b, fc3W, fc3b, (float*)d_out);
}

// Round 26
// 282.479 us; speedup vs baseline: 1.0850x; 1.0850x over previous
//
#include <hip/hip_runtime.h>

#define N_NODES 100000
#define N_EDGES 1600000
#define N_GRAPHS 256
#define NBKT 196                          // ceil(100000/512) buckets of 512 nodes
#define BKT_CAP 16384                     // slots per bucket region (expected fill ~8192)
#define BCHUNKS 391                       // ceil(1600000/4096) bucket-role blocks
#define MM1_BLOCKS 3125                   // 100000 / 32 exactly
#define A_BLOCKS (BCHUNKS + MM1_BLOCKS)   // 3516: bid%9==0 -> bucket, else mm1

__device__ __forceinline__ float lrelu(float v) { return v > 0.f ? v : 0.01f * v; }

// bf16 storage helpers (RNE)
__device__ __forceinline__ unsigned short f2bf(float f) {
    unsigned int u = __float_as_uint(f);
    return (unsigned short)((u + 0x7FFFu + ((u >> 16) & 1u)) >> 16);
}
__device__ __forceinline__ float bf2f(unsigned short h) {
    return __uint_as_float(((unsigned int)h) << 16);
}
__device__ __forceinline__ float blo(unsigned int v) { return __uint_as_float(v << 16); }
__device__ __forceinline__ float bhi(unsigned int v) { return __uint_as_float(v & 0xFFFF0000u); }

// ============ FUSED phase A: bucket edges by dst/512  ∥  matmul L1 ============
// Bucket role caches dst/src in registers across both passes (one global read).
// mm1 role reads xs via float4 (1 b128 per 4 k's, conflict-free banks).
__global__ void bucket_and_mm1(const int* __restrict__ src, const int* __restrict__ dst,
                               int* __restrict__ bucketCnt, unsigned int* __restrict__ bkt,
                               const float* __restrict__ x, const float* __restrict__ W1,
                               unsigned short* __restrict__ T1) {
    __shared__ float lds[32 * 132 + 128 * 16];   // 25088 B, unioned across roles
    int bid = blockIdx.x;
    int tid = threadIdx.x;
    if (bid % 9 == 0) {
        // ---- bucket role ----
        int* lcnt = (int*)lds;            // [4][196]
        int* loff = lcnt + 784;           // [4][196]
        int* lcnt2 = loff + 784;          // [4][196]
        int fi = bid / 9;                 // 0..390
        for (int i = tid; i < 784; i += 256) { lcnt[i] = 0; lcnt2[i] = 0; }
        __syncthreads();
        int sub = tid & 3;
        int e0 = fi * 4096 + tid;
        int dcache[16], scache[16];
#pragma unroll
        for (int i = 0; i < 16; ++i) {
            int e = e0 + i * 256;
            if (e < N_EDGES) {
                dcache[i] = dst[e];
                scache[i] = src[e];
                atomicAdd(&lcnt[sub * 196 + (dcache[i] >> 9)], 1);
            }
        }
        __syncthreads();
        if (tid < NBKT) {
            int c0 = lcnt[tid], c1 = lcnt[196 + tid], c2 = lcnt[392 + tid], c3 = lcnt[588 + tid];
            int tot = c0 + c1 + c2 + c3;
            int goff = (tot > 0) ? atomicAdd(&bucketCnt[tid], tot) : 0;
            loff[tid] = goff;
            loff[196 + tid] = goff + c0;
            loff[392 + tid] = goff + c0 + c1;
            loff[588 + tid] = goff + c0 + c1 + c2;
        }
        __syncthreads();
#pragma unroll
        for (int i = 0; i < 16; ++i) {
            int e = e0 + i * 256;
            if (e < N_EDGES) {
                int d = dcache[i];
                int b = d >> 9;
                int pos = loff[sub * 196 + b] + atomicAdd(&lcnt2[sub * 196 + b], 1);
                if (pos < BKT_CAP)   // capacity guard (uniform dst: never hit)
                    bkt[(size_t)b * BKT_CAP + pos] =
                        ((unsigned int)(d & 511) << 17) | (unsigned int)scache[i];
            }
        }
    } else {
        // ---- mm1 role: T1 = x @ W1 [128->16], 32-node tile, float4 xs reads ----
        int mb = bid - bid / 9 - 1;       // 0..3124
        float* xs = lds;                  // 32 rows x 132 (padded, 16B-aligned rows)
        float* wsm = lds + 32 * 132;      // 128 x 16 (original layout)
        const int n0 = mb * 32;           // 32*3125 = 100000 exactly
        for (int i = tid; i < 128 * 16; i += 256) wsm[i] = W1[i];
        const float4* X4 = (const float4*)x;     // 32 float4 per row
        for (int i = tid; i < 32 * 32; i += 256) {
            int r2 = i >> 5, c = i & 31;
            ((float4*)(xs + r2 * 132))[c] = X4[(size_t)(n0 + r2) * 32 + c];
        }
        __syncthreads();
        int r2 = tid >> 3, jp = tid & 7;  // 32 rows x 8 pairs = 256 outputs
        float a0 = 0.f, a1 = 0.f;
        const float4* xr4 = (const float4*)(xs + r2 * 132);
#pragma unroll
        for (int k4 = 0; k4 < 32; ++k4) {
            float4 xv = xr4[k4];
            float2 w0 = *(const float2*)(wsm + (4 * k4 + 0) * 16 + 2 * jp);
            float2 w1 = *(const float2*)(wsm + (4 * k4 + 1) * 16 + 2 * jp);
            float2 w2 = *(const float2*)(wsm + (4 * k4 + 2) * 16 + 2 * jp);
            float2 w3 = *(const float2*)(wsm + (4 * k4 + 3) * 16 + 2 * jp);
            a0 = fmaf(xv.x, w0.x, a0); a1 = fmaf(xv.x, w0.y, a1);
            a0 = fmaf(xv.y, w1.x, a0); a1 = fmaf(xv.y, w1.y, a1);
            a0 = fmaf(xv.z, w2.x, a0); a1 = fmaf(xv.z, w2.y, a1);
            a0 = fmaf(xv.w, w3.x, a0); a1 = fmaf(xv.w, w3.y, a1);
        }
        ((unsigned int*)T1)[(size_t)(n0 + r2) * 8 + jp] = ((unsigned int)f2bf(a1) << 16) | f2bf(a0);
    }
}

// ============ per-bucket: scan counts -> degrees -> base -> scatter adj ============
__global__ void build_bucket(const unsigned int* __restrict__ bkt, const int* __restrict__ bucketCnt,
                             int* __restrict__ base, int* __restrict__ adj) {
    __shared__ int ldeg[512];
    __shared__ int lofs[512];
    __shared__ int ssum[256];
    int b = blockIdx.x;
    int tid = threadIdx.x;
    // exclusive prefix of bucketCnt over buckets < b  (196 values, scan in LDS)
    ssum[tid] = (tid < NBKT) ? bucketCnt[tid] : 0;
    __syncthreads();
    for (int off = 1; off < 256; off <<= 1) {
        int add = (tid >= off) ? ssum[tid - off] : 0;
        __syncthreads();
        ssum[tid] += add;
        __syncthreads();
    }
    int gbase = (b > 0) ? ssum[b - 1] : 0;
    int cnt = min(((b < NBKT) ? bucketCnt[b] : 0), BKT_CAP);
    int nstart = b * 512;
    int nn = min(512, N_NODES - nstart);
    const unsigned int* seg = bkt + (size_t)b * BKT_CAP;
    for (int i = tid; i < 512; i += 256) ldeg[i] = 0;
    __syncthreads();
    for (int e = tid; e < cnt; e += 256) atomicAdd(&ldeg[seg[e] >> 17], 1);
    __syncthreads();
    // exclusive scan of ldeg[0..511] with 256 threads (2 elems/thread)
    int a0 = ldeg[2 * tid], a1 = ldeg[2 * tid + 1];
    __syncthreads();
    ssum[tid] = a0 + a1;
    __syncthreads();
    for (int off = 1; off < 256; off <<= 1) {
        int add = (tid >= off) ? ssum[tid - off] : 0;
        __syncthreads();
        ssum[tid] += add;
        __syncthreads();
    }
    int prev = (tid > 0) ? ssum[tid - 1] : 0;
    lofs[2 * tid] = prev;
    lofs[2 * tid + 1] = prev + a0;
    __syncthreads();
    // write base (coalesced)
    for (int i = tid; i < nn; i += 256) base[nstart + i] = gbase + lofs[i];
    if (b == 0 && tid == 0) base[N_NODES] = N_EDGES;
    // reset ldeg as cursors, then scatter
    for (int i = tid; i < 512; i += 256) ldeg[i] = 0;
    __syncthreads();
    for (int e = tid; e < cnt; e += 256) {
        unsigned int v = seg[e];
        int dl = (int)(v >> 17);
        int pos = atomicAdd(&ldeg[dl], 1);
        adj[gbase + lofs[dl] + pos] = (int)(v & 0x1FFFFu);
    }
}

// ============ register-tiled matmul: X[N,DIN]@W[DIN,DOUT] -> bf16 rows ============
template <int DIN, int DOUT, int ROWS, bool BIAS, bool RELU>
__global__ void matmul_rt(const unsigned int* __restrict__ X2, const float* __restrict__ W,
                          unsigned short* __restrict__ T, const float* __restrict__ bias) {
    constexpr int PAIRS = DOUT / 2;              // 16, 32, 25
    constexpr int PT = (PAIRS + 3) / 4;          // pair-tiles: 4, 8, 7
    constexpr int RT = ROWS / 4;                 // row-tiles
    constexpr int XST = DIN + 1;                 // odd stride -> conflict-light
    __shared__ float xs[ROWS * XST];
    __shared__ float wsm[DIN * DOUT + 8];        // +8: pad-jp reads stay in-bounds
    const int n0 = blockIdx.x * ROWS;
    const bool full = (n0 + ROWS <= N_NODES);
    int tid = threadIdx.x;
    for (int i = tid; i < DIN * DOUT; i += 256) wsm[i] = W[i];
    constexpr int V = DIN / 2;                   // uints per row
    for (int i = tid; i < ROWS * V; i += 256) {
        int r = i / V, c = i - r * V;
        int node = n0 + r;
        unsigned int v = (full || node < N_NODES) ? X2[(size_t)node * V + c] : 0u;
        xs[r * XST + 2 * c]     = blo(v);
        xs[r * XST + 2 * c + 1] = bhi(v);
    }
    __syncthreads();
    if (tid >= RT * PT) return;
    int rt = tid / PT, pt = tid - rt * PT;
    const float* xr0 = xs + (rt * 4) * XST;
    const float* wp = wsm + 2 * (pt * 4);
    float2 acc[4][4];
#pragma unroll
    for (int i = 0; i < 4; ++i)
#pragma unroll
        for (int j = 0; j < 4; ++j) acc[i][j] = make_float2(0.f, 0.f);
#pragma unroll 4
    for (int k = 0; k < DIN; ++k) {
        float xv0 = xr0[k];
        float xv1 = xr0[XST + k];
        float xv2 = xr0[2 * XST + k];
        float xv3 = xr0[3 * XST + k];
        const float* wr = wp + k * DOUT;
        float2 w0 = *(const float2*)(wr);
        float2 w1 = *(const float2*)(wr + 2);
        float2 w2 = *(const float2*)(wr + 4);
        float2 w3 = *(const float2*)(wr + 6);
        acc[0][0].x = fmaf(xv0, w0.x, acc[0][0].x); acc[0][0].y = fmaf(xv0, w0.y, acc[0][0].y);
        acc[0][1].x = fmaf(xv0, w1.x, acc[0][1].x); acc[0][1].y = fmaf(xv0, w1.y, acc[0][1].y);
        acc[0][2].x = fmaf(xv0, w2.x, acc[0][2].x); acc[0][2].y = fmaf(xv0, w2.y, acc[0][2].y);
        acc[0][3].x = fmaf(xv0, w3.x, acc[0][3].x); acc[0][3].y = fmaf(xv0, w3.y, acc[0][3].y);
        acc[1][0].x = fmaf(xv1, w0.x, acc[1][0].x); acc[1][0].y = fmaf(xv1, w0.y, acc[1][0].y);
        acc[1][1].x = fmaf(xv1, w1.x, acc[1][1].x); acc[1][1].y = fmaf(xv1, w1.y, acc[1][1].y);
        acc[1][2].x = fmaf(xv1, w2.x, acc[1][2].x); acc[1][2].y = fmaf(xv1, w2.y, acc[1][2].y);
        acc[1][3].x = fmaf(xv1, w3.x, acc[1][3].x); acc[1][3].y = fmaf(xv1, w3.y, acc[1][3].y);
        acc[2][0].x = fmaf(xv2, w0.x, acc[2][0].x); acc[2][0].y = fmaf(xv2, w0.y, acc[2][0].y);
        acc[2][1].x = fmaf(xv2, w1.x, acc[2][1].x); acc[2][1].y = fmaf(xv2, w1.y, acc[2][1].y);
        acc[2][2].x = fmaf(xv2, w2.x, acc[2][2].x); acc[2][2].y = fmaf(xv2, w2.y, acc[2][2].y);
        acc[2][3].x = fmaf(xv2, w3.x, acc[2][3].x); acc[2][3].y = fmaf(xv2, w3.y, acc[2][3].y);
        acc[3][0].x = fmaf(xv3, w0.x, acc[3][0].x); acc[3][0].y = fmaf(xv3, w0.y, acc[3][0].y);
        acc[3][1].x = fmaf(xv3, w1.x, acc[3][1].x); acc[3][1].y = fmaf(xv3, w1.y, acc[3][1].y);
        acc[3][2].x = fmaf(xv3, w2.x, acc[3][2].x); acc[3][2].y = fmaf(xv3, w2.y, acc[3][2].y);
        acc[3][3].x = fmaf(xv3, w3.x, acc[3][3].x); acc[3][3].y = fmaf(xv3, w3.y, acc[3][3].y);
    }
    unsigned int* Tu = (unsigned int*)T;
#pragma unroll
    for (int i = 0; i < 4; ++i) {
        int node = n0 + rt * 4 + i;
        if (full || node < N_NODES) {
#pragma unroll
            for (int j = 0; j < 4; ++j) {
                int jp = pt * 4 + j;
                if (PAIRS % 4 == 0 || jp < PAIRS) {
                    float a0 = acc[i][j].x, a1 = acc[i][j].y;
                    if (BIAS) { a0 += bias[2 * jp]; a1 += bias[2 * jp + 1]; }
                    if (RELU) { a0 = lrelu(a0); a1 = lrelu(a1); }
                    Tu[(size_t)node * PAIRS + jp] = ((unsigned int)f2bf(a1) << 16) | f2bf(a0);
                }
            }
        }
    }
}

// ============ CSR gather-aggregate (bf16 pairs), 8-deep ILP ============
template <int DOUT, bool BIAS, bool RELU>
__global__ void gather_agg_bf16(const unsigned short* __restrict__ T, const int* __restrict__ base,
                                const int* __restrict__ adj, const float* __restrict__ b,
                                unsigned short* __restrict__ out) {
    constexpr int PAIRS = DOUT / 2;                       // 8, 16, 25
    int gi = blockIdx.x * 256 + threadIdx.x;
    int node = gi / PAIRS;                                // const div -> magic mul
    int j = gi - node * PAIRS;
    if (node >= N_NODES) return;
    const unsigned int* Tu = (const unsigned int*)T;
    int e0 = base[node], e1 = base[node + 1];
    float a0 = 0.f, a1 = 0.f, c0 = 0.f, c1 = 0.f;
    int k = e0;
    for (; k + 7 < e1; k += 8) {
        int s0 = adj[k], s1 = adj[k + 1], s2 = adj[k + 2], s3 = adj[k + 3];
        int s4 = adj[k + 4], s5 = adj[k + 5], s6 = adj[k + 6], s7 = adj[k + 7];
        unsigned int v0 = Tu[(size_t)s0 * PAIRS + j];
        unsigned int v1 = Tu[(size_t)s1 * PAIRS + j];
        unsigned int v2 = Tu[(size_t)s2 * PAIRS + j];
        unsigned int v3 = Tu[(size_t)s3 * PAIRS + j];
        unsigned int v4 = Tu[(size_t)s4 * PAIRS + j];
        unsigned int v5 = Tu[(size_t)s5 * PAIRS + j];
        unsigned int v6 = Tu[(size_t)s6 * PAIRS + j];
        unsigned int v7 = Tu[(size_t)s7 * PAIRS + j];
        a0 += blo(v0); a1 += bhi(v0);
        c0 += blo(v1); c1 += bhi(v1);
        a0 += blo(v2); a1 += bhi(v2);
        c0 += blo(v3); c1 += bhi(v3);
        a0 += blo(v4); a1 += bhi(v4);
        c0 += blo(v5); c1 += bhi(v5);
        a0 += blo(v6); a1 += bhi(v6);
        c0 += blo(v7); c1 += bhi(v7);
    }
    for (; k + 3 < e1; k += 4) {
        int s0 = adj[k], s1 = adj[k + 1], s2 = adj[k + 2], s3 = adj[k + 3];
        unsigned int v0 = Tu[(size_t)s0 * PAIRS + j];
        unsigned int v1 = Tu[(size_t)s1 * PAIRS + j];
        unsigned int v2 = Tu[(size_t)s2 * PAIRS + j];
        unsigned int v3 = Tu[(size_t)s3 * PAIRS + j];
        a0 += blo(v0); a1 += bhi(v0);
        c0 += blo(v1); c1 += bhi(v1);
        a0 += blo(v2); a1 += bhi(v2);
        c0 += blo(v3); c1 += bhi(v3);
    }
    for (; k < e1; ++k) {
        int s = adj[k];
        unsigned int v = Tu[(size_t)s * PAIRS + j];
        a0 += blo(v); a1 += bhi(v);
    }
    a0 += c0; a1 += c1;
    if (BIAS) { a0 += b[2 * j]; a1 += b[2 * j + 1]; }
    if (RELU) { a0 = lrelu(a0); a1 = lrelu(a1); }
    ((unsigned int*)out)[(size_t)node * PAIRS + j] = ((unsigned int)f2bf(a1) << 16) | f2bf(a0);
}

// ============ BatchNorm stats (bf16 row input) ============
__global__ void bn_partial_kernel(const unsigned short* __restrict__ H, float* __restrict__ sum,
                                  float* __restrict__ ssum) {
    int tid = threadIdx.x;
    int j = tid % 50;
    int sub = tid / 50;
    float s = 0.f, ss = 0.f;
    if (tid < 250) {
        for (int node = blockIdx.x * 5 + sub; node < N_NODES; node += gridDim.x * 5) {
            float v = bf2f(H[(size_t)node * 50 + j]);
            s += v;
            ss += v * v;
        }
    }
    __shared__ float ls[256], lss[256];
    ls[tid] = s;
    lss[tid] = ss;
    __syncthreads();
    if (tid < 50) {
        float a = ls[tid] + ls[tid + 50] + ls[tid + 100] + ls[tid + 150] + ls[tid + 200];
        float c = lss[tid] + lss[tid + 50] + lss[tid + 100] + lss[tid + 150] + lss[tid + 200];
        atomicAdd(&sum[tid], a);
        atomicAdd(&ssum[tid], c);
    }
}

// ============ setup: graph bounds (batch sorted) + zero bucketCnt/bnsum/bnssum ============
__global__ void setup_kernel(const int* __restrict__ batch, int* __restrict__ bounds,
                             int* __restrict__ bucketCnt, float* __restrict__ bnsum,
                             float* __restrict__ bnssum) {
    int tid = threadIdx.x;
    if (blockIdx.x == 0) {
        bucketCnt[tid] = 0;
    } else if (tid < 64) {
        bnsum[tid] = 0.f;
        bnssum[tid] = 0.f;
    }
    int g = blockIdx.x * 256 + tid;
    if (g > N_GRAPHS) return;
    int lo = 0, hi = N_NODES;
    while (lo < hi) {
        int mid = (lo + hi) >> 1;
        if (batch[mid] < g) lo = mid + 1; else hi = mid;
    }
    bounds[g] = lo;
}

// ============ BN finalize (inline) + lrelu + segmented pool: one block per graph ============
__global__ void pool_seg_kernel(const unsigned short* __restrict__ H, const int* __restrict__ bounds,
                                const float* __restrict__ bnsum, const float* __restrict__ bnssum,
                                const float* __restrict__ gamma, const float* __restrict__ beta,
                                float* __restrict__ G) {
    int g = blockIdx.x;
    int s = bounds[g], e = bounds[g + 1];
    int tid = threadIdx.x;
    int j = tid % 50;
    int sub = tid / 50;     // 0..4 for tid<250
    float acc = 0.f;
    if (tid < 250) {
        float m = bnsum[j] / (float)N_NODES;
        float var = bnssum[j] / (float)N_NODES - m * m;
        float rs = rsqrtf(fmaxf(var, 0.f) + 1e-5f);
        float scale = rs * gamma[j];
        float shift = beta[j] - m * scale;
        for (int n = s + sub; n < e; n += 5) {
            float v = fmaf(bf2f(H[(size_t)n * 50 + j]), scale, shift);
            acc += lrelu(v);
        }
    }
    __shared__ float ls[256];
    ls[tid] = acc;
    __syncthreads();
    if (tid < 50) {
        G[g * 50 + tid] = ls[tid] + ls[tid + 50] + ls[tid + 100] + ls[tid + 150] + ls[tid + 200];
    }
}

// ============ MLP head: 8 blocks x 32 graphs, weights staged in LDS ============
__global__ void mlp_kernel(const float* __restrict__ G,
                           const float* __restrict__ fc1W, const float* __restrict__ fc1b,
                           const float* __restrict__ fc2W, const float* __restrict__ fc2b,
                           const float* __restrict__ fc3W, const float* __restrict__ fc3b,
                           float* __restrict__ out) {
    __shared__ float lw[2192];   // fc1W 1500 | fc1b 30 | fc2W 600 | fc2b 20 | fc3W 40 | fc3b 2
    int tid = threadIdx.x;
    for (int i = tid; i < 1500; i += 256) lw[i] = fc1W[i];
    for (int i = tid; i < 30; i += 256) lw[1500 + i] = fc1b[i];
    for (int i = tid; i < 600; i += 256) lw[1530 + i] = fc2W[i];
    for (int i = tid; i < 20; i += 256) lw[2130 + i] = fc2b[i];
    for (int i = tid; i < 40; i += 256) lw[2150 + i] = fc3W[i];
    for (int i = tid; i < 2; i += 256) lw[2190 + i] = fc3b[i];
    __syncthreads();
    int g = blockIdx.x * 32 + tid;
    if (tid >= 32 || g >= N_GRAPHS) return;
    float a[50];
#pragma unroll
    for (int k = 0; k < 50; ++k) a[k] = G[g * 50 + k];
    float h1[30];
#pragma unroll
    for (int j = 0; j < 30; ++j) {
        float acc = lw[1500 + j];
#pragma unroll
        for (int k = 0; k < 50; ++k) acc = fmaf(a[k], lw[k * 30 + j], acc);
        h1[j] = lrelu(acc);
    }
    float h2[20];
#pragma unroll
    for (int j = 0; j < 20; ++j) {
        float acc = lw[2130 + j];
#pragma unroll
        for (int k = 0; k < 30; ++k) acc = fmaf(h1[k], lw[1530 + k * 20 + j], acc);
        h2[j] = lrelu(acc);
    }
    float z0 = lw[2190], z1 = lw[2191];
#pragma unroll
    for (int k = 0; k < 20; ++k) {
        z0 = fmaf(h2[k], lw[2150 + k * 2 + 0], z0);
        z1 = fmaf(h2[k], lw[2150 + k * 2 + 1], z1);
    }
    float m = fmaxf(z0, z1);
    float lse = m + logf(expf(z0 - m) + expf(z1 - m));
    out[g * 2 + 0] = z0 - lse;
    out[g * 2 + 1] = z1 - lse;
}

extern "C" void kernel_launch(void* const* d_in, const int* in_sizes, int n_in,
                              void* d_out, int out_size, void* d_ws, size_t ws_size,
                              hipStream_t stream) {
    const float* x     = (const float*)d_in[0];
    const int*   ei    = (const int*)d_in[1];
    const int*   batch = (const int*)d_in[2];
    const float* W1 = (const float*)d_in[3];  const float* b1 = (const float*)d_in[4];
    const float* W2 = (const float*)d_in[5];  const float* b2 = (const float*)d_in[6];
    const float* W3 = (const float*)d_in[7];  const float* b3 = (const float*)d_in[8];
    const float* W4 = (const float*)d_in[9];  const float* b4 = (const float*)d_in[10];
    const float* bng = (const float*)d_in[11]; const float* bnb = (const float*)d_in[12];
    const float* fc1W = (const float*)d_in[13]; const float* fc1b = (const float*)d_in[14];
    const float* fc2W = (const float*)d_in[15]; const float* fc2b = (const float*)d_in[16];
    const float* fc3W = (const float*)d_in[17]; const float* fc3b = (const float*)d_in[18];

    const int* src = ei;
    const int* dst = ei + N_EDGES;

    // ---- workspace layout ----
    char* w = (char*)d_ws;
    unsigned short* bufA = (unsigned short*)w;      w += (size_t)6400000 * 2;  // 12.8 MB
    unsigned short* bufB = (unsigned short*)w;      w += (size_t)6400000 * 2;  // 12.8 MB
    int*   adj  = (int*)w;                          w += (size_t)N_EDGES * 4;  // 6.4 MB
    unsigned int* bkt = (unsigned int*)w;           w += (size_t)NBKT * BKT_CAP * 4;  // 12.8 MB
    int*   base = (int*)w;                          w += (size_t)(N_NODES + 1) * 4;
    int*   bucketCnt = (int*)w;                     w += 256 * 4;
    float* bnsum = (float*)w;                       w += 64 * 4;
    float* bnssum = (float*)w;                      w += 64 * 4;
    int*   bounds = (int*)w;                        w += (N_GRAPHS + 1) * 4;
    float* G    = (float*)w;                        w += (size_t)N_GRAPHS * 50 * 4;

    dim3 blk(256);

    // ---- setup: bounds + zero bucketCnt/bn accumulators (one kernel) ----
    setup_kernel<<<2, 256, 0, stream>>>(batch, bounds, bucketCnt, bnsum, bnssum);

    // ---- FUSED phase A: 512-node-bucket edges ∥ matmul L1 (x@W1 -> T1) ----
    bucket_and_mm1<<<A_BLOCKS, blk, 0, stream>>>(src, dst, bucketCnt, bkt, x, W1, bufA);

    // ---- per-bucket degree/scan/base/scatter ----
    build_bucket<<<NBKT, blk, 0, stream>>>(bkt, bucketCnt, base, adj);

    // ---- L1 agg: h1 = lrelu(agg(T1) + b1) ----
    gather_agg_bf16<16, true, true><<<(N_NODES * 8 + 255) / 256, blk, 0, stream>>>(bufA, base, adj, b1, bufB);

    // ---- L2: s2 = agg(h1); h2 = lrelu(s2 @ W2 + b2) [16->32] ----
    gather_agg_bf16<16, false, false><<<(N_NODES * 8 + 255) / 256, blk, 0, stream>>>(bufB, base, adj, nullptr, bufA);
    matmul_rt<16, 32, 256, true, true><<<(N_NODES + 255) / 256, blk, 0, stream>>>((const unsigned int*)bufA, W2, bufB, b2);

    // ---- L3: s3 = agg(h2); h3 = lrelu(s3 @ W3 + b3) [32->64] ----
    gather_agg_bf16<32, false, false><<<(N_NODES * 16 + 255) / 256, blk, 0, stream>>>(bufB, base, adj, nullptr, bufA);
    matmul_rt<32, 64, 128, true, true><<<(N_NODES + 127) / 128, blk, 0, stream>>>((const unsigned int*)bufA, W3, bufB, b3);

    // ---- L4: T4 = h3 @ W4 [64->50]; h4 = agg(T4) + b4 ----
    matmul_rt<64, 50, 128, false, false><<<(N_NODES + 127) / 128, blk, 0, stream>>>((const unsigned int*)bufB, W4, bufA, nullptr);
    gather_agg_bf16<50, true, false><<<(N_NODES * 25 + 255) / 256, blk, 0, stream>>>(bufA, base, adj, b4, bufB);

    // ---- BatchNorm stats ----
    bn_partial_kernel<<<256, blk, 0, stream>>>(bufB, bnsum, bnssum);

    // ---- BN finalize (inline) + lrelu + segmented pool (no atomics) ----
    pool_seg_kernel<<<N_GRAPHS, blk, 0, stream>>>(bufB, bounds, bnsum, bnssum, bng, bnb, G);

    // ---- MLP head ----
    mlp_kernel<<<8, 256, 0, stream>>>(G, fc1W, fc1b, fc2W, fc2b, fc3W, fc3b, (float*)d_out);
}

// Round 27
// 278.472 us; speedup vs baseline: 1.1006x; 1.0144x over previous
//
#include <hip/hip_runtime.h>

#define N_NODES 100000
#define N_EDGES 1600000
#define N_GRAPHS 256
#define NBKT 196                          // ceil(100000/512) buckets of 512 nodes
#define BKT_CAP 16384                     // slots per bucket region (expected fill ~8192)
#define BCHUNKS 391                       // ceil(1600000/4096) bucket-role blocks
#define MM1_BLOCKS 3125                   // 100000 / 32 exactly
#define A_BLOCKS (BCHUNKS + MM1_BLOCKS)   // 3516: bid%9==0 -> bucket, else mm1

__device__ __forceinline__ float lrelu(float v) { return v > 0.f ? v : 0.01f * v; }

// bf16 storage helpers (RNE)
__device__ __forceinline__ unsigned short f2bf(float f) {
    unsigned int u = __float_as_uint(f);
    return (unsigned short)((u + 0x7FFFu + ((u >> 16) & 1u)) >> 16);
}
__device__ __forceinline__ float bf2f(unsigned short h) {
    return __uint_as_float(((unsigned int)h) << 16);
}
__device__ __forceinline__ float blo(unsigned int v) { return __uint_as_float(v << 16); }
__device__ __forceinline__ float bhi(unsigned int v) { return __uint_as_float(v & 0xFFFF0000u); }
__device__ __forceinline__ unsigned int pk(float a0, float a1) {
    return ((unsigned int)f2bf(a1) << 16) | f2bf(a0);
}

// ============ FUSED phase A: bucket edges by dst/512  ∥  matmul L1 ============
__global__ void bucket_and_mm1(const int* __restrict__ src, const int* __restrict__ dst,
                               int* __restrict__ bucketCnt, unsigned int* __restrict__ bkt,
                               const float* __restrict__ x, const float* __restrict__ W1,
                               unsigned short* __restrict__ T1) {
    __shared__ float lds[32 * 132 + 128 * 16];   // 25088 B, unioned across roles
    int bid = blockIdx.x;
    int tid = threadIdx.x;
    if (bid % 9 == 0) {
        // ---- bucket role: dst/src cached in regs across both passes ----
        int* lcnt = (int*)lds;            // [4][196]
        int* loff = lcnt + 784;           // [4][196]
        int* lcnt2 = loff + 784;          // [4][196]
        int fi = bid / 9;                 // 0..390
        for (int i = tid; i < 784; i += 256) { lcnt[i] = 0; lcnt2[i] = 0; }
        __syncthreads();
        int sub = tid & 3;
        int e0 = fi * 4096 + tid;
        int dcache[16], scache[16];
#pragma unroll
        for (int i = 0; i < 16; ++i) {
            int e = e0 + i * 256;
            if (e < N_EDGES) {
                dcache[i] = dst[e];
                scache[i] = src[e];
                atomicAdd(&lcnt[sub * 196 + (dcache[i] >> 9)], 1);
            }
        }
        __syncthreads();
        if (tid < NBKT) {
            int c0 = lcnt[tid], c1 = lcnt[196 + tid], c2 = lcnt[392 + tid], c3 = lcnt[588 + tid];
            int tot = c0 + c1 + c2 + c3;
            int goff = (tot > 0) ? atomicAdd(&bucketCnt[tid], tot) : 0;
            loff[tid] = goff;
            loff[196 + tid] = goff + c0;
            loff[392 + tid] = goff + c0 + c1;
            loff[588 + tid] = goff + c0 + c1 + c2;
        }
        __syncthreads();
#pragma unroll
        for (int i = 0; i < 16; ++i) {
            int e = e0 + i * 256;
            if (e < N_EDGES) {
                int d = dcache[i];
                int b = d >> 9;
                int pos = loff[sub * 196 + b] + atomicAdd(&lcnt2[sub * 196 + b], 1);
                if (pos < BKT_CAP)   // capacity guard (uniform dst: never hit)
                    bkt[(size_t)b * BKT_CAP + pos] =
                        ((unsigned int)(d & 511) << 17) | (unsigned int)scache[i];
            }
        }
    } else {
        // ---- mm1 role: T1 = x @ W1 [128->16], 32-node tile, float4 xs reads ----
        int mb = bid - bid / 9 - 1;       // 0..3124
        float* xs = lds;                  // 32 rows x 132 (padded, 16B-aligned rows)
        float* wsm = lds + 32 * 132;      // 128 x 16 (original layout)
        const int n0 = mb * 32;           // 32*3125 = 100000 exactly
        for (int i = tid; i < 128 * 16; i += 256) wsm[i] = W1[i];
        const float4* X4 = (const float4*)x;     // 32 float4 per row
        for (int i = tid; i < 32 * 32; i += 256) {
            int r2 = i >> 5, c = i & 31;
            ((float4*)(xs + r2 * 132))[c] = X4[(size_t)(n0 + r2) * 32 + c];
        }
        __syncthreads();
        int r2 = tid >> 3, jp = tid & 7;  // 32 rows x 8 pairs = 256 outputs
        float a0 = 0.f, a1 = 0.f;
        const float4* xr4 = (const float4*)(xs + r2 * 132);
#pragma unroll
        for (int k4 = 0; k4 < 32; ++k4) {
            float4 xv = xr4[k4];
            float2 w0 = *(const float2*)(wsm + (4 * k4 + 0) * 16 + 2 * jp);
            float2 w1 = *(const float2*)(wsm + (4 * k4 + 1) * 16 + 2 * jp);
            float2 w2 = *(const float2*)(wsm + (4 * k4 + 2) * 16 + 2 * jp);
            float2 w3 = *(const float2*)(wsm + (4 * k4 + 3) * 16 + 2 * jp);
            a0 = fmaf(xv.x, w0.x, a0); a1 = fmaf(xv.x, w0.y, a1);
            a0 = fmaf(xv.y, w1.x, a0); a1 = fmaf(xv.y, w1.y, a1);
            a0 = fmaf(xv.z, w2.x, a0); a1 = fmaf(xv.z, w2.y, a1);
            a0 = fmaf(xv.w, w3.x, a0); a1 = fmaf(xv.w, w3.y, a1);
        }
        ((unsigned int*)T1)[(size_t)(n0 + r2) * 8 + jp] = pk(a0, a1);
    }
}

// ============ per-bucket: scan counts -> degrees -> base -> scatter adj ============
__global__ void build_bucket(const unsigned int* __restrict__ bkt, const int* __restrict__ bucketCnt,
                             int* __restrict__ base, int* __restrict__ adj) {
    __shared__ int ldeg[512];
    __shared__ int lofs[512];
    __shared__ int ssum[256];
    int b = blockIdx.x;
    int tid = threadIdx.x;
    ssum[tid] = (tid < NBKT) ? bucketCnt[tid] : 0;
    __syncthreads();
    for (int off = 1; off < 256; off <<= 1) {
        int add = (tid >= off) ? ssum[tid - off] : 0;
        __syncthreads();
        ssum[tid] += add;
        __syncthreads();
    }
    int gbase = (b > 0) ? ssum[b - 1] : 0;
    int cnt = min(((b < NBKT) ? bucketCnt[b] : 0), BKT_CAP);
    int nstart = b * 512;
    int nn = min(512, N_NODES - nstart);
    const unsigned int* seg = bkt + (size_t)b * BKT_CAP;
    for (int i = tid; i < 512; i += 256) ldeg[i] = 0;
    __syncthreads();
    for (int e = tid; e < cnt; e += 256) atomicAdd(&ldeg[seg[e] >> 17], 1);
    __syncthreads();
    int a0 = ldeg[2 * tid], a1 = ldeg[2 * tid + 1];
    __syncthreads();
    ssum[tid] = a0 + a1;
    __syncthreads();
    for (int off = 1; off < 256; off <<= 1) {
        int add = (tid >= off) ? ssum[tid - off] : 0;
        __syncthreads();
        ssum[tid] += add;
        __syncthreads();
    }
    int prev = (tid > 0) ? ssum[tid - 1] : 0;
    lofs[2 * tid] = prev;
    lofs[2 * tid + 1] = prev + a0;
    __syncthreads();
    for (int i = tid; i < nn; i += 256) base[nstart + i] = gbase + lofs[i];
    if (b == 0 && tid == 0) base[N_NODES] = N_EDGES;
    for (int i = tid; i < 512; i += 256) ldeg[i] = 0;
    __syncthreads();
    for (int e = tid; e < cnt; e += 256) {
        unsigned int v = seg[e];
        int dl = (int)(v >> 17);
        int pos = atomicAdd(&ldeg[dl], 1);
        adj[gbase + lofs[dl] + pos] = (int)(v & 0x1FFFFu);
    }
}

// ============ register-tiled matmul: X[N,DIN]@W[DIN,DOUT] -> bf16 rows (stride PSTRIDE) ============
template <int DIN, int DOUT, int ROWS, int PSTRIDE, bool BIAS, bool RELU>
__global__ void matmul_rt(const unsigned int* __restrict__ X2, const float* __restrict__ W,
                          unsigned short* __restrict__ T, const float* __restrict__ bias) {
    constexpr int PAIRS = DOUT / 2;              // 16, 32, 25
    constexpr int PT = (PAIRS + 3) / 4;          // pair-tiles: 4, 8, 7
    constexpr int RT = ROWS / 4;                 // row-tiles
    constexpr int XST = DIN + 1;                 // odd stride -> conflict-light
    __shared__ float xs[ROWS * XST];
    __shared__ float wsm[DIN * DOUT + 8];        // +8: pad-jp reads stay in-bounds
    const int n0 = blockIdx.x * ROWS;
    const bool full = (n0 + ROWS <= N_NODES);
    int tid = threadIdx.x;
    for (int i = tid; i < DIN * DOUT; i += 256) wsm[i] = W[i];
    constexpr int V = DIN / 2;                   // uints per row
    for (int i = tid; i < ROWS * V; i += 256) {
        int r = i / V, c = i - r * V;
        int node = n0 + r;
        unsigned int v = (full || node < N_NODES) ? X2[(size_t)node * V + c] : 0u;
        xs[r * XST + 2 * c]     = blo(v);
        xs[r * XST + 2 * c + 1] = bhi(v);
    }
    __syncthreads();
    if (tid >= RT * PT) return;
    int rt = tid / PT, pt = tid - rt * PT;
    const float* xr0 = xs + (rt * 4) * XST;
    const float* wp = wsm + 2 * (pt * 4);
    float2 acc[4][4];
#pragma unroll
    for (int i = 0; i < 4; ++i)
#pragma unroll
        for (int j = 0; j < 4; ++j) acc[i][j] = make_float2(0.f, 0.f);
#pragma unroll 4
    for (int k = 0; k < DIN; ++k) {
        float xv0 = xr0[k];
        float xv1 = xr0[XST + k];
        float xv2 = xr0[2 * XST + k];
        float xv3 = xr0[3 * XST + k];
        const float* wr = wp + k * DOUT;
        float2 w0 = *(const float2*)(wr);
        float2 w1 = *(const float2*)(wr + 2);
        float2 w2 = *(const float2*)(wr + 4);
        float2 w3 = *(const float2*)(wr + 6);
        acc[0][0].x = fmaf(xv0, w0.x, acc[0][0].x); acc[0][0].y = fmaf(xv0, w0.y, acc[0][0].y);
        acc[0][1].x = fmaf(xv0, w1.x, acc[0][1].x); acc[0][1].y = fmaf(xv0, w1.y, acc[0][1].y);
        acc[0][2].x = fmaf(xv0, w2.x, acc[0][2].x); acc[0][2].y = fmaf(xv0, w2.y, acc[0][2].y);
        acc[0][3].x = fmaf(xv0, w3.x, acc[0][3].x); acc[0][3].y = fmaf(xv0, w3.y, acc[0][3].y);
        acc[1][0].x = fmaf(xv1, w0.x, acc[1][0].x); acc[1][0].y = fmaf(xv1, w0.y, acc[1][0].y);
        acc[1][1].x = fmaf(xv1, w1.x, acc[1][1].x); acc[1][1].y = fmaf(xv1, w1.y, acc[1][1].y);
        acc[1][2].x = fmaf(xv1, w2.x, acc[1][2].x); acc[1][2].y = fmaf(xv1, w2.y, acc[1][2].y);
        acc[1][3].x = fmaf(xv1, w3.x, acc[1][3].x); acc[1][3].y = fmaf(xv1, w3.y, acc[1][3].y);
        acc[2][0].x = fmaf(xv2, w0.x, acc[2][0].x); acc[2][0].y = fmaf(xv2, w0.y, acc[2][0].y);
        acc[2][1].x = fmaf(xv2, w1.x, acc[2][1].x); acc[2][1].y = fmaf(xv2, w1.y, acc[2][1].y);
        acc[2][2].x = fmaf(xv2, w2.x, acc[2][2].x); acc[2][2].y = fmaf(xv2, w2.y, acc[2][2].y);
        acc[2][3].x = fmaf(xv2, w3.x, acc[2][3].x); acc[2][3].y = fmaf(xv2, w3.y, acc[2][3].y);
        acc[3][0].x = fmaf(xv3, w0.x, acc[3][0].x); acc[3][0].y = fmaf(xv3, w0.y, acc[3][0].y);
        acc[3][1].x = fmaf(xv3, w1.x, acc[3][1].x); acc[3][1].y = fmaf(xv3, w1.y, acc[3][1].y);
        acc[3][2].x = fmaf(xv3, w2.x, acc[3][2].x); acc[3][2].y = fmaf(xv3, w2.y, acc[3][2].y);
        acc[3][3].x = fmaf(xv3, w3.x, acc[3][3].x); acc[3][3].y = fmaf(xv3, w3.y, acc[3][3].y);
    }
    unsigned int* Tu = (unsigned int*)T;
#pragma unroll
    for (int i = 0; i < 4; ++i) {
        int node = n0 + rt * 4 + i;
        if (full || node < N_NODES) {
#pragma unroll
            for (int j = 0; j < 4; ++j) {
                int jp = pt * 4 + j;
                if (PAIRS % 4 == 0 || jp < PAIRS) {
                    float a0 = acc[i][j].x, a1 = acc[i][j].y;
                    if (BIAS) { a0 += bias[2 * jp]; a1 += bias[2 * jp + 1]; }
                    if (RELU) { a0 = lrelu(a0); a1 = lrelu(a1); }
                    Tu[(size_t)node * PSTRIDE + jp] = pk(a0, a1);
                }
            }
        }
    }
}

// ============ CSR gather-aggregate, uint2 lanes (2 pairs/lane), 8-deep ILP ============
// PSIN/PSOUT: row strides in uints (even). Lane j handles pairs 2j, 2j+1.
template <int DOUT, int PSIN, int PSOUT, bool BIAS, bool RELU>
__global__ void gather_u2(const unsigned short* __restrict__ T, const int* __restrict__ base,
                          const int* __restrict__ adj, const float* __restrict__ b,
                          unsigned short* __restrict__ out) {
    constexpr int PAIRS = DOUT / 2;               // 8, 16, 25
    constexpr int HALF = (PAIRS + 1) / 2;         // lanes per node: 4, 8, 13
    constexpr int H2 = PSIN / 2;                  // uint2 per input row
    int gi = blockIdx.x * 256 + threadIdx.x;
    int node = gi / HALF;                         // const div -> magic mul
    int j = gi - node * HALF;
    if (node >= N_NODES) return;
    const uint2* Tu2 = (const uint2*)T;
    int e0 = base[node], e1 = base[node + 1];
    float a0 = 0.f, a1 = 0.f, a2 = 0.f, a3 = 0.f;
    float c0 = 0.f, c1 = 0.f, c2 = 0.f, c3 = 0.f;
    int k = e0;
    for (; k + 7 < e1; k += 8) {
        int s0 = adj[k], s1 = adj[k + 1], s2 = adj[k + 2], s3 = adj[k + 3];
        int s4 = adj[k + 4], s5 = adj[k + 5], s6 = adj[k + 6], s7 = adj[k + 7];
        uint2 v0 = Tu2[(size_t)s0 * H2 + j];
        uint2 v1 = Tu2[(size_t)s1 * H2 + j];
        uint2 v2 = Tu2[(size_t)s2 * H2 + j];
        uint2 v3 = Tu2[(size_t)s3 * H2 + j];
        uint2 v4 = Tu2[(size_t)s4 * H2 + j];
        uint2 v5 = Tu2[(size_t)s5 * H2 + j];
        uint2 v6 = Tu2[(size_t)s6 * H2 + j];
        uint2 v7 = Tu2[(size_t)s7 * H2 + j];
        a0 += blo(v0.x); a1 += bhi(v0.x); a2 += blo(v0.y); a3 += bhi(v0.y);
        c0 += blo(v1.x); c1 += bhi(v1.x); c2 += blo(v1.y); c3 += bhi(v1.y);
        a0 += blo(v2.x); a1 += bhi(v2.x); a2 += blo(v2.y); a3 += bhi(v2.y);
        c0 += blo(v3.x); c1 += bhi(v3.x); c2 += blo(v3.y); c3 += bhi(v3.y);
        a0 += blo(v4.x); a1 += bhi(v4.x); a2 += blo(v4.y); a3 += bhi(v4.y);
        c0 += blo(v5.x); c1 += bhi(v5.x); c2 += blo(v5.y); c3 += bhi(v5.y);
        a0 += blo(v6.x); a1 += bhi(v6.x); a2 += blo(v6.y); a3 += bhi(v6.y);
        c0 += blo(v7.x); c1 += bhi(v7.x); c2 += blo(v7.y); c3 += bhi(v7.y);
    }
    for (; k + 3 < e1; k += 4) {
        int s0 = adj[k], s1 = adj[k + 1], s2 = adj[k + 2], s3 = adj[k + 3];
        uint2 v0 = Tu2[(size_t)s0 * H2 + j];
        uint2 v1 = Tu2[(size_t)s1 * H2 + j];
        uint2 v2 = Tu2[(size_t)s2 * H2 + j];
        uint2 v3 = Tu2[(size_t)s3 * H2 + j];
        a0 += blo(v0.x); a1 += bhi(v0.x); a2 += blo(v0.y); a3 += bhi(v0.y);
        c0 += blo(v1.x); c1 += bhi(v1.x); c2 += blo(v1.y); c3 += bhi(v1.y);
        a0 += blo(v2.x); a1 += bhi(v2.x); a2 += blo(v2.y); a3 += bhi(v2.y);
        c0 += blo(v3.x); c1 += bhi(v3.x); c2 += blo(v3.y); c3 += bhi(v3.y);
    }
    for (; k < e1; ++k) {
        int s = adj[k];
        uint2 v = Tu2[(size_t)s * H2 + j];
        a0 += blo(v.x); a1 += bhi(v.x); a2 += blo(v.y); a3 += bhi(v.y);
    }
    a0 += c0; a1 += c1; a2 += c2; a3 += c3;
    bool p1ok = ((PAIRS & 1) == 0) || (j < HALF - 1);   // last lane of odd-PAIRS: pair1 is pad
    if (BIAS) {
        a0 += b[4 * j]; a1 += b[4 * j + 1];
        if (p1ok) { a2 += b[4 * j + 2]; a3 += b[4 * j + 3]; }
    }
    if (RELU) { a0 = lrelu(a0); a1 = lrelu(a1); a2 = lrelu(a2); a3 = lrelu(a3); }
    uint2 o;
    o.x = pk(a0, a1);
    o.y = pk(a2, a3);
    ((uint2*)out)[(size_t)node * (PSOUT / 2) + j] = o;   // pad slot write harmless
}

// ============ BatchNorm stats (bf16 rows, stride 52 shorts) ============
__global__ void bn_partial_kernel(const unsigned short* __restrict__ H, float* __restrict__ sum,
                                  float* __restrict__ ssum) {
    int tid = threadIdx.x;
    int j = tid % 50;
    int sub = tid / 50;
    float s = 0.f, ss = 0.f;
    if (tid < 250) {
        for (int node = blockIdx.x * 5 + sub; node < N_NODES; node += gridDim.x * 5) {
            float v = bf2f(H[(size_t)node * 52 + j]);
            s += v;
            ss += v * v;
        }
    }
    __shared__ float ls[256], lss[256];
    ls[tid] = s;
    lss[tid] = ss;
    __syncthreads();
    if (tid < 50) {
        float a = ls[tid] + ls[tid + 50] + ls[tid + 100] + ls[tid + 150] + ls[tid + 200];
        float c = lss[tid] + lss[tid + 50] + lss[tid + 100] + lss[tid + 150] + lss[tid + 200];
        atomicAdd(&sum[tid], a);
        atomicAdd(&ssum[tid], c);
    }
}

// ============ setup: graph bounds (batch sorted) + zero bucketCnt/bnsum/bnssum ============
__global__ void setup_kernel(const int* __restrict__ batch, int* __restrict__ bounds,
                             int* __restrict__ bucketCnt, float* __restrict__ bnsum,
                             float* __restrict__ bnssum) {
    int tid = threadIdx.x;
    if (blockIdx.x == 0) {
        bucketCnt[tid] = 0;
    } else if (tid < 64) {
        bnsum[tid] = 0.f;
        bnssum[tid] = 0.f;
    }
    int g = blockIdx.x * 256 + tid;
    if (g > N_GRAPHS) return;
    int lo = 0, hi = N_NODES;
    while (lo < hi) {
        int mid = (lo + hi) >> 1;
        if (batch[mid] < g) lo = mid + 1; else hi = mid;
    }
    bounds[g] = lo;
}

// ============ BN finalize (inline) + lrelu + segmented pool (stride 52 input) ============
__global__ void pool_seg_kernel(const unsigned short* __restrict__ H, const int* __restrict__ bounds,
                                const float* __restrict__ bnsum, const float* __restrict__ bnssum,
                                const float* __restrict__ gamma, const float* __restrict__ beta,
                                float* __restrict__ G) {
    int g = blockIdx.x;
    int s = bounds[g], e = bounds[g + 1];
    int tid = threadIdx.x;
    int j = tid % 50;
    int sub = tid / 50;     // 0..4 for tid<250
    float acc = 0.f;
    if (tid < 250) {
        float m = bnsum[j] / (float)N_NODES;
        float var = bnssum[j] / (float)N_NODES - m * m;
        float rs = rsqrtf(fmaxf(var, 0.f) + 1e-5f);
        float scale = rs * gamma[j];
        float shift = beta[j] - m * scale;
        for (int n = s + sub; n < e; n += 5) {
            float v = fmaf(bf2f(H[(size_t)n * 52 + j]), scale, shift);
            acc += lrelu(v);
        }
    }
    __shared__ float ls[256];
    ls[tid] = acc;
    __syncthreads();
    if (tid < 50) {
        G[g * 50 + tid] = ls[tid] + ls[tid + 50] + ls[tid + 100] + ls[tid + 150] + ls[tid + 200];
    }
}

// ============ MLP head: 8 blocks x 32 graphs, weights staged in LDS ============
__global__ void mlp_kernel(const float* __restrict__ G,
                           const float* __restrict__ fc1W, const float* __restrict__ fc1b,
                           const float* __restrict__ fc2W, const float* __restrict__ fc2b,
                           const float* __restrict__ fc3W, const float* __restrict__ fc3b,
                           float* __restrict__ out) {
    __shared__ float lw[2192];   // fc1W 1500 | fc1b 30 | fc2W 600 | fc2b 20 | fc3W 40 | fc3b 2
    int tid = threadIdx.x;
    for (int i = tid; i < 1500; i += 256) lw[i] = fc1W[i];
    for (int i = tid; i < 30; i += 256) lw[1500 + i] = fc1b[i];
    for (int i = tid; i < 600; i += 256) lw[1530 + i] = fc2W[i];
    for (int i = tid; i < 20; i += 256) lw[2130 + i] = fc2b[i];
    for (int i = tid; i < 40; i += 256) lw[2150 + i] = fc3W[i];
    for (int i = tid; i < 2; i += 256) lw[2190 + i] = fc3b[i];
    __syncthreads();
    int g = blockIdx.x * 32 + tid;
    if (tid >= 32 || g >= N_GRAPHS) return;
    float a[50];
#pragma unroll
    for (int k = 0; k < 50; ++k) a[k] = G[g * 50 + k];
    float h1[30];
#pragma unroll
    for (int j = 0; j < 30; ++j) {
        float acc = lw[1500 + j];
#pragma unroll
        for (int k = 0; k < 50; ++k) acc = fmaf(a[k], lw[k * 30 + j], acc);
        h1[j] = lrelu(acc);
    }
    float h2[20];
#pragma unroll
    for (int j = 0; j < 20; ++j) {
        float acc = lw[2130 + j];
#pragma unroll
        for (int k = 0; k < 30; ++k) acc = fmaf(h1[k], lw[1530 + k * 20 + j], acc);
        h2[j] = lrelu(acc);
    }
    float z0 = lw[2190], z1 = lw[2191];
#pragma unroll
    for (int k = 0; k < 20; ++k) {
        z0 = fmaf(h2[k], lw[2150 + k * 2 + 0], z0);
        z1 = fmaf(h2[k], lw[2150 + k * 2 + 1], z1);
    }
    float m = fmaxf(z0, z1);
    float lse = m + logf(expf(z0 - m) + expf(z1 - m));
    out[g * 2 + 0] = z0 - lse;
    out[g * 2 + 1] = z1 - lse;
}

extern "C" void kernel_launch(void* const* d_in, const int* in_sizes, int n_in,
                              void* d_out, int out_size, void* d_ws, size_t ws_size,
                              hipStream_t stream) {
    const float* x     = (const float*)d_in[0];
    const int*   ei    = (const int*)d_in[1];
    const int*   batch = (const int*)d_in[2];
    const float* W1 = (const float*)d_in[3];  const float* b1 = (const float*)d_in[4];
    const float* W2 = (const float*)d_in[5];  const float* b2 = (const float*)d_in[6];
    const float* W3 = (const float*)d_in[7];  const float* b3 = (const float*)d_in[8];
    const float* W4 = (const float*)d_in[9];  const float* b4 = (const float*)d_in[10];
    const float* bng = (const float*)d_in[11]; const float* bnb = (const float*)d_in[12];
    const float* fc1W = (const float*)d_in[13]; const float* fc1b = (const float*)d_in[14];
    const float* fc2W = (const float*)d_in[15]; const float* fc2b = (const float*)d_in[16];
    const float* fc3W = (const float*)d_in[17]; const float* fc3b = (const float*)d_in[18];

    const int* src = ei;
    const int* dst = ei + N_EDGES;

    // ---- workspace layout ----
    char* w = (char*)d_ws;
    unsigned short* bufA = (unsigned short*)w;      w += (size_t)6400000 * 2;  // 12.8 MB
    unsigned short* bufB = (unsigned short*)w;      w += (size_t)6400000 * 2;  // 12.8 MB
    int*   adj  = (int*)w;                          w += (size_t)N_EDGES * 4;  // 6.4 MB
    unsigned int* bkt = (unsigned int*)w;           w += (size_t)NBKT * BKT_CAP * 4;  // 12.8 MB
    int*   base = (int*)w;                          w += (size_t)(N_NODES + 1) * 4;
    int*   bucketCnt = (int*)w;                     w += 256 * 4;
    float* bnsum = (float*)w;                       w += 64 * 4;
    float* bnssum = (float*)w;                      w += 64 * 4;
    int*   bounds = (int*)w;                        w += (N_GRAPHS + 1) * 4;
    float* G    = (float*)w;                        w += (size_t)N_GRAPHS * 50 * 4;

    dim3 blk(256);

    // ---- setup: bounds + zero bucketCnt/bn accumulators (one kernel) ----
    setup_kernel<<<2, 256, 0, stream>>>(batch, bounds, bucketCnt, bnsum, bnssum);

    // ---- FUSED phase A: 512-node-bucket edges ∥ matmul L1 (x@W1 -> T1) ----
    bucket_and_mm1<<<A_BLOCKS, blk, 0, stream>>>(src, dst, bucketCnt, bkt, x, W1, bufA);

    // ---- per-bucket degree/scan/base/scatter ----
    build_bucket<<<NBKT, blk, 0, stream>>>(bkt, bucketCnt, base, adj);

    // ---- L1 agg: h1 = lrelu(agg(T1) + b1)   [stride 8 -> 8] ----
    gather_u2<16, 8, 8, true, true><<<(N_NODES * 4 + 255) / 256, blk, 0, stream>>>(bufA, base, adj, b1, bufB);

    // ---- L2: s2 = agg(h1) [8->8]; h2 = lrelu(s2 @ W2 + b2) [16->32, stride 16] ----
    gather_u2<16, 8, 8, false, false><<<(N_NODES * 4 + 255) / 256, blk, 0, stream>>>(bufB, base, adj, nullptr, bufA);
    matmul_rt<16, 32, 256, 16, true, true><<<(N_NODES + 255) / 256, blk, 0, stream>>>((const unsigned int*)bufA, W2, bufB, b2);

    // ---- L3: s3 = agg(h2) [16->16]; h3 = lrelu(s3 @ W3 + b3) [32->64, stride 32] ----
    gather_u2<32, 16, 16, false, false><<<(N_NODES * 8 + 255) / 256, blk, 0, stream>>>(bufB, base, adj, nullptr, bufA);
    matmul_rt<32, 64, 128, 32, true, true><<<(N_NODES + 127) / 128, blk, 0, stream>>>((const unsigned int*)bufA, W3, bufB, b3);

    // ---- L4: T4 = h3 @ W4 [64->50, stride 26]; h4 = agg(T4) + b4 [26->26] ----
    matmul_rt<64, 50, 128, 26, false, false><<<(N_NODES + 127) / 128, blk, 0, stream>>>((const unsigned int*)bufB, W4, bufA, nullptr);
    gather_u2<50, 26, 26, true, false><<<(N_NODES * 13 + 255) / 256, blk, 0, stream>>>(bufA, base, adj, b4, bufB);

    // ---- BatchNorm stats (stride 52 shorts) ----
    bn_partial_kernel<<<256, blk, 0, stream>>>(bufB, bnsum, bnssum);

    // ---- BN finalize (inline) + lrelu + segmented pool (no atomics) ----
    pool_seg_kernel<<<N_GRAPHS, blk, 0, stream>>>(bufB, bounds, bnsum, bnssum, bng, bnb, G);

    // ---- MLP head ----
    mlp_kernel<<<8, 256, 0, stream>>>(G, fc1W, fc1b, fc2W, fc2b, fc3W, fc3b, (float*)d_out);
}